// Round 3
// baseline (139.269 us; speedup 1.0000x reference)
//
#include <hip/hip_runtime.h>
#include <stdint.h>

// ---------------------------------------------------------------------------
// Bottleneck with 3x3 local self-attention, MI355X (gfx950).
// R2: d_out is FLOAT32 (out_npz 35.4MB > bf16 raw 33.5MB proves it).
//     conv3 epilogue now writes f32 across the full 67MB buffer.
// Layout: activations (pix, C) bf16 so every 1x1 conv is gemm_bt:
//   D[o][P] = sum_k W[o][k] * Act[P][k], MFMA 16x16x32 bf16.
// Pipeline: transpose+cast x (into d_out 1st half, dead before conv3) ->
//   conv1 -> q,k,v -> attn -> conv3(+residual, f32 out).
// ws layout (32 MiB): h1t@0 (8MiB, aliased by att after qkv), q@8, k@16, v@24.
// ---------------------------------------------------------------------------

typedef __attribute__((ext_vector_type(4))) float f32x4;
typedef __attribute__((ext_vector_type(8))) __bf16 bf16x8;
typedef __attribute__((ext_vector_type(4))) unsigned short u16x4;
typedef __attribute__((ext_vector_type(8))) unsigned short u16x8;

__device__ __forceinline__ float bf2f(unsigned short u) {
  union { unsigned int i; float f; } c; c.i = ((unsigned int)u) << 16; return c.f;
}
__device__ __forceinline__ unsigned short f2bf(float f) {
  union { float f; unsigned int i; } c; c.f = f;
  unsigned int x = c.i;
  return (unsigned short)((x + 0x7FFFu + ((x >> 16) & 1u)) >> 16);
}

// ---------------------------------------------------------------------------
// x (16,1024ch,1024pix) f32 -> xt (16,1024pix,1024ch) bf16, LDS tile transpose.
__global__ __launch_bounds__(256) void k_transpose_x(const float* __restrict__ x,
                                                     unsigned short* __restrict__ xt) {
  __shared__ float tile[32][33];
  const int b  = blockIdx.z;
  const int c0 = blockIdx.y * 32;
  const int p0 = blockIdx.x * 32;
  const int tx = threadIdx.x & 31;
  const int ty = threadIdx.x >> 5;  // 0..7
  const float* xb = x + (size_t)b * 1048576;
  unsigned short* xtb = xt + (size_t)b * 1048576;
#pragma unroll
  for (int i = 0; i < 4; ++i)
    tile[ty + i * 8][tx] = xb[(size_t)(c0 + ty + i * 8) * 1024 + p0 + tx];
  __syncthreads();
#pragma unroll
  for (int i = 0; i < 4; ++i)
    xtb[(size_t)(p0 + ty + i * 8) * 1024 + c0 + tx] = f2bf(tile[tx][ty + i * 8]);
}

// ---------------------------------------------------------------------------
// gemm_bt: D[o][P] = sum_k A[o][k]*B[P][k].
// A: (M x K) f32 row-major weights (converted to bf16 during staging).
// B: (N x K) bf16 row-major activations.
// 128x128 tile, BK=32, 4 waves (2x2), 64x64 per wave, register staging.
// MODE 0: Cout (u16*): Cout[P*256 + o] = bf16( relu?(acc*s + b) )  (pix-major)
// MODE 1: Cout (f32*): d_out[b][o][pix] = relu(acc*s + b + resid)  (f32!)
template <int MODE>
__global__ __launch_bounds__(256, 2) void k_gemm(
    const float* __restrict__ A, const unsigned short* __restrict__ B,
    void* __restrict__ CoutV, const float* __restrict__ scale,
    const float* __restrict__ bias, const float* __restrict__ resid,
    int K, int do_relu) {
  __shared__ unsigned short lA[128 * 32];
  __shared__ unsigned short lB[128 * 32];
  const int m0  = blockIdx.y * 128;
  const int n0  = blockIdx.x * 128;
  const int tid = threadIdx.x;
  const int lane = tid & 63;
  const int wid  = tid >> 6;
  const int wm = (wid >> 1) * 64, wn = (wid & 1) * 64;
  const int fr = lane & 15, fq = lane >> 4;

  f32x4 acc[4][4] = {};

  // staging map: thread t -> row r = t>>1 (0..127), cols h..h+15 (h = 0 or 16)
  const int r = tid >> 1;
  const int h = (tid & 1) * 16;
  const float*          Ag = A + (size_t)(m0 + r) * K + h;
  const unsigned short* Bg = B + (size_t)(n0 + r) * K + h;
  unsigned short* lAw = &lA[r * 32 + h];
  unsigned short* lBw = &lB[r * 32 + h];

  for (int k0 = 0; k0 < K; k0 += 32) {
    // global -> regs (issued before the barrier for overlap)
    f32x4 a4[4];
#pragma unroll
    for (int i = 0; i < 4; ++i) a4[i] = *(const f32x4*)(Ag + k0 + i * 4);
    u16x8 b0 = *(const u16x8*)(Bg + k0);
    u16x8 b1 = *(const u16x8*)(Bg + k0 + 8);
    u16x8 ap0, ap1;
#pragma unroll
    for (int i = 0; i < 8; ++i) ap0[i] = f2bf(a4[i >> 2][i & 3]);
#pragma unroll
    for (int i = 0; i < 8; ++i) ap1[i] = f2bf(a4[2 + (i >> 2)][i & 3]);

    __syncthreads();  // prior iteration's LDS reads complete before overwrite
    *(u16x8*)lAw = ap0;
    *(u16x8*)(lAw + 8) = ap1;
    *(u16x8*)lBw = b0;
    *(u16x8*)(lBw + 8) = b1;
    __syncthreads();  // LDS tile complete

    bf16x8 af[4], bb[4];
#pragma unroll
    for (int i = 0; i < 4; ++i)
      af[i] = *(const bf16x8*)&lA[(wm + i * 16 + fr) * 32 + fq * 8];
#pragma unroll
    for (int j = 0; j < 4; ++j)
      bb[j] = *(const bf16x8*)&lB[(wn + j * 16 + fr) * 32 + fq * 8];
#pragma unroll
    for (int i = 0; i < 4; ++i)
#pragma unroll
      for (int j = 0; j < 4; ++j)
        acc[i][j] = __builtin_amdgcn_mfma_f32_16x16x32_bf16(af[i], bb[j], acc[i][j], 0, 0, 0);
  }

#pragma unroll
  for (int i = 0; i < 4; ++i) {
    const int ob = m0 + wm + i * 16 + fq * 4;   // o base, multiple of 4
    const f32x4 s4 = *(const f32x4*)&scale[ob];
    const f32x4 b4 = *(const f32x4*)&bias[ob];
#pragma unroll
    for (int j = 0; j < 4; ++j) {
      const int P = n0 + wn + j * 16 + fr;
      if (MODE == 0) {
        unsigned short* Cout = (unsigned short*)CoutV;
        u16x4 pk;
#pragma unroll
        for (int rr = 0; rr < 4; ++rr) {
          float v = acc[i][j][rr] * s4[rr] + b4[rr];
          if (do_relu) v = fmaxf(v, 0.0f);
          pk[rr] = f2bf(v);
        }
        *(u16x4*)&Cout[(size_t)P * 256 + ob] = pk;
      } else {
        float* Cout = (float*)CoutV;
        const size_t base = (size_t)(P >> 10) * 1048576 + (size_t)(P & 1023);
#pragma unroll
        for (int rr = 0; rr < 4; ++rr) {
          const size_t addr = base + (size_t)(ob + rr) * 1024;
          float v = acc[i][j][rr] * s4[rr] + b4[rr] + resid[addr];
          Cout[addr] = fmaxf(v, 0.0f);
        }
      }
    }
  }
}

// ---------------------------------------------------------------------------
// Local 3x3 attention. Thread = (pixel slot s=tid>>5, head g=tid&31).
// S_t = q.k_nb + q.ph(i) + q.pw(j)  (k_nb = 0 when OOB; pos term always added).
// softmax over 9 taps; out = sum_t attn_t * v_nb (v_nb = 0 OOB); relu(bn(out)).
__global__ __launch_bounds__(256, 4) void k_attn(
    const unsigned short* __restrict__ Q, const unsigned short* __restrict__ Kb,
    const unsigned short* __restrict__ Vb, unsigned short* __restrict__ O,
    const float* __restrict__ pos_h, const float* __restrict__ pos_w,
    const float* __restrict__ bs, const float* __restrict__ bb) {
  __shared__ float ph_l[3][256];
  __shared__ float pw_l[3][256];
  {
    const int c = threadIdx.x;
#pragma unroll
    for (int i = 0; i < 3; ++i) {
      ph_l[i][c] = pos_h[c * 3 + i];
      pw_l[i][c] = pos_w[c * 3 + i];
    }
  }
  __syncthreads();
  const int tid = threadIdx.x;
  const int g = tid & 31, s = tid >> 5;
  const int P = blockIdx.x * 8 + s;
  const int b = P >> 10, pix = P & 1023;
  const int hh = pix >> 5, ww = pix & 31;
  const int c0 = g * 8;

  float qf[8];
  {
    u16x8 qv = *(const u16x8*)&Q[(size_t)P * 256 + c0];
#pragma unroll
    for (int d = 0; d < 8; ++d) qf[d] = bf2f(qv[d]);
  }
  float Ai[3], Bj[3];
#pragma unroll
  for (int i = 0; i < 3; ++i) {
    float a = 0.f, w = 0.f;
#pragma unroll
    for (int d = 0; d < 8; ++d) {
      a += qf[d] * ph_l[i][c0 + d];
      w += qf[d] * pw_l[i][c0 + d];
    }
    Ai[i] = a; Bj[i] = w;
  }

  float S[9];
  int nPs[9];
#pragma unroll
  for (int t = 0; t < 9; ++t) {
    const int di = t / 3, dj = t % 3;
    const int nh = hh + di - 1, nw = ww + dj - 1;
    float sum = Ai[di] + Bj[dj];
    int nP = -1;
    if ((unsigned)nh < 32u && (unsigned)nw < 32u) {
      nP = (b << 10) + (nh << 5) + nw;
      u16x8 kv = *(const u16x8*)&Kb[(size_t)nP * 256 + c0];
#pragma unroll
      for (int d = 0; d < 8; ++d) sum += qf[d] * bf2f(kv[d]);
    }
    nPs[t] = nP;
    S[t] = sum;
  }

  float mx = S[0];
#pragma unroll
  for (int t = 1; t < 9; ++t) mx = fmaxf(mx, S[t]);
  float e[9], tot = 0.f;
#pragma unroll
  for (int t = 0; t < 9; ++t) { e[t] = __expf(S[t] - mx); tot += e[t]; }
  const float inv = 1.0f / tot;

  float of[8] = {0.f, 0.f, 0.f, 0.f, 0.f, 0.f, 0.f, 0.f};
#pragma unroll
  for (int t = 0; t < 9; ++t) {
    if (nPs[t] >= 0) {
      u16x8 vv = *(const u16x8*)&Vb[(size_t)nPs[t] * 256 + c0];
      const float w = e[t] * inv;
#pragma unroll
      for (int d = 0; d < 8; ++d) of[d] += w * bf2f(vv[d]);
    }
  }

  u16x8 res;
#pragma unroll
  for (int d = 0; d < 8; ++d) {
    float v = of[d] * bs[c0 + d] + bb[c0 + d];
    v = fmaxf(v, 0.0f);
    res[d] = f2bf(v);
  }
  *(u16x8*)&O[(size_t)P * 256 + c0] = res;
}

// ---------------------------------------------------------------------------
extern "C" void kernel_launch(void* const* d_in, const int* in_sizes, int n_in,
                              void* d_out, int out_size, void* d_ws, size_t ws_size,
                              hipStream_t stream) {
  (void)in_sizes; (void)n_in; (void)out_size; (void)ws_size;
  const float* x       = (const float*)d_in[0];
  const float* w1      = (const float*)d_in[1];
  const float* bn1_s   = (const float*)d_in[2];
  const float* bn1_b   = (const float*)d_in[3];
  const float* wq      = (const float*)d_in[4];
  const float* bnq_s   = (const float*)d_in[5];
  const float* bnq_b   = (const float*)d_in[6];
  const float* wk      = (const float*)d_in[7];
  const float* bnk_s   = (const float*)d_in[8];
  const float* bnk_b   = (const float*)d_in[9];
  const float* wv      = (const float*)d_in[10];
  const float* bnv_s   = (const float*)d_in[11];
  const float* bnv_b   = (const float*)d_in[12];
  const float* pos_h   = (const float*)d_in[13];
  const float* pos_w   = (const float*)d_in[14];
  const float* bnatt_s = (const float*)d_in[15];
  const float* bnatt_b = (const float*)d_in[16];
  const float* w3      = (const float*)d_in[17];
  const float* bn3_s   = (const float*)d_in[18];
  const float* bn3_b   = (const float*)d_in[19];

  // ws (32 MiB): h1t@0 (dead after v-GEMM; att aliases), q@8MiB, k@16MiB, v@24MiB.
  // xt (16Mpix x 1024ch bf16 = 32MiB) staged in d_out's FIRST HALF (d_out is
  // f32, 64MiB); xt is dead before conv3 overwrites d_out.
  char* ws = (char*)d_ws;
  unsigned short* h1t = (unsigned short*)(ws);
  unsigned short* qt  = (unsigned short*)(ws + 8388608);
  unsigned short* ktt = (unsigned short*)(ws + 16777216);
  unsigned short* vtt = (unsigned short*)(ws + 25165824);
  unsigned short* att = h1t;
  unsigned short* xt  = (unsigned short*)d_out;

  k_transpose_x<<<dim3(32, 32, 16), dim3(256), 0, stream>>>(x, xt);

  // conv1: h1t[P][o] = relu(bn1(W1 . x)),  M=256, N=16384, K=1024
  k_gemm<0><<<dim3(128, 2), dim3(256), 0, stream>>>(w1, xt, h1t, bn1_s, bn1_b,
                                                    nullptr, 1024, 1);
  // q, k, v: M=256, N=16384, K=256
  k_gemm<0><<<dim3(128, 2), dim3(256), 0, stream>>>(wq, h1t, qt, bnq_s, bnq_b,
                                                    nullptr, 256, 1);
  k_gemm<0><<<dim3(128, 2), dim3(256), 0, stream>>>(wk, h1t, ktt, bnk_s, bnk_b,
                                                    nullptr, 256, 1);
  k_gemm<0><<<dim3(128, 2), dim3(256), 0, stream>>>(wv, h1t, vtt, bnv_s, bnv_b,
                                                    nullptr, 256, 0);

  k_attn<<<dim3(2048), dim3(256), 0, stream>>>(qt, ktt, vtt, att, pos_h, pos_w,
                                               bnatt_s, bnatt_b);

  // conv3 + residual + relu -> d_out (f32), M=1024, N=16384, K=256
  k_gemm<1><<<dim3(128, 8), dim3(256), 0, stream>>>(w3, att, d_out,
                                                    bn3_s, bn3_b, x, 256, 1);
}

// Round 4
// 118.071 us; speedup vs baseline: 1.1795x; 1.1795x over previous
//
#include <hip/hip_runtime.h>
#include <stdint.h>

// ---------------------------------------------------------------------------
// Bottleneck with 3x3 local self-attention, MI355X (gfx950).
// R3 passed at 139us; conv1 GEMM was 47us at 6% MfmaUtil / 10% occupancy
// (256 blocks = 1/CU, full latency exposure) + 8-way LDS bank conflicts.
// R4: 64x64 tile (4x more blocks), double-buffered LDS with register
// prefetch (1 barrier/K-step), XOR-swizzled LDS (8-way -> 2-way floor).
// Layout: activations (pix, C) bf16; every 1x1 conv is gemm_bt:
//   D[o][P] = sum_k W[o][k] * Act[P][k], MFMA 16x16x32 bf16.
// ws (32 MiB): h1t@0 (att aliases after qkv), q@8MiB, k@16MiB, v@24MiB.
// xt (32MiB bf16) staged in d_out's first half (f32 64MiB), dead before conv3.
// ---------------------------------------------------------------------------

typedef __attribute__((ext_vector_type(4))) float f32x4;
typedef __attribute__((ext_vector_type(8))) __bf16 bf16x8;
typedef __attribute__((ext_vector_type(4))) unsigned short u16x4;
typedef __attribute__((ext_vector_type(8))) unsigned short u16x8;

__device__ __forceinline__ float bf2f(unsigned short u) {
  union { unsigned int i; float f; } c; c.i = ((unsigned int)u) << 16; return c.f;
}
__device__ __forceinline__ unsigned short f2bf(float f) {
  union { float f; unsigned int i; } c; c.f = f;
  unsigned int x = c.i;
  return (unsigned short)((x + 0x7FFFu + ((x >> 16) & 1u)) >> 16);
}

// ---------------------------------------------------------------------------
// x (16,1024ch,1024pix) f32 -> xt (16,1024pix,1024ch) bf16, LDS tile transpose.
__global__ __launch_bounds__(256) void k_transpose_x(const float* __restrict__ x,
                                                     unsigned short* __restrict__ xt) {
  __shared__ float tile[32][33];
  const int b  = blockIdx.z;
  const int c0 = blockIdx.y * 32;
  const int p0 = blockIdx.x * 32;
  const int tx = threadIdx.x & 31;
  const int ty = threadIdx.x >> 5;  // 0..7
  const float* xb = x + (size_t)b * 1048576;
  unsigned short* xtb = xt + (size_t)b * 1048576;
#pragma unroll
  for (int i = 0; i < 4; ++i)
    tile[ty + i * 8][tx] = xb[(size_t)(c0 + ty + i * 8) * 1024 + p0 + tx];
  __syncthreads();
#pragma unroll
  for (int i = 0; i < 4; ++i)
    xtb[(size_t)(p0 + ty + i * 8) * 1024 + c0 + tx] = f2bf(tile[tx][ty + i * 8]);
}

// ---------------------------------------------------------------------------
// gemm_bt: D[o][P] = sum_k A[o][k]*B[P][k].
// A: (M x K) f32 weights (bf16-converted during staging). B: (N x K) bf16.
// 64x64 tile, BK=32, 4 waves (2x2), 32x32/wave. Double-buffered LDS,
// register prefetch, one barrier per K-step. LDS col-group XOR swizzle
// (g ^= row&3) on both write and read -> 2-way (free) bank aliasing.
// MODE 0: Cout (u16*): Cout[P*256 + o] = bf16( relu?(acc*s + b) )
// MODE 1: Cout (f32*): d_out[b][o][pix] = relu(acc*s + b + resid), resid f32.
template <int MODE>
__global__ __launch_bounds__(256, 4) void k_gemm(
    const float* __restrict__ A, const unsigned short* __restrict__ B,
    void* __restrict__ CoutV, const float* __restrict__ scale,
    const float* __restrict__ bias, const float* __restrict__ resid,
    int K, int do_relu) {
  __shared__ unsigned short lA[2][64 * 32];
  __shared__ unsigned short lB[2][64 * 32];
  const int m0  = blockIdx.y * 64;
  const int n0  = blockIdx.x * 64;
  const int tid = threadIdx.x;
  const int lane = tid & 63;
  const int wid  = tid >> 6;
  const int wm = (wid >> 1) * 32, wn = (wid & 1) * 32;
  const int fr = lane & 15, fq = lane >> 4;

  f32x4 acc[2][2] = {};

  // staging map: thread t -> row r = t>>2 (0..63), col-group g = t&3 (8 cols)
  const int r = tid >> 2;
  const int g = tid & 3;
  const float*          Ag = A + (size_t)(m0 + r) * K + g * 8;
  const unsigned short* Bg = B + (size_t)(n0 + r) * K + g * 8;
  const int lofs = r * 32 + (g ^ (r & 3)) * 8;   // swizzled LDS slot

  f32x4 a4[2];
  u16x8 bv;
  a4[0] = *(const f32x4*)(Ag);
  a4[1] = *(const f32x4*)(Ag + 4);
  bv    = *(const u16x8*)(Bg);

  int p = 0;
  for (int k0 = 0; k0 < K; k0 += 32, p ^= 1) {
    u16x8 ap;
#pragma unroll
    for (int i = 0; i < 8; ++i) ap[i] = f2bf(a4[i >> 2][i & 3]);
    *(u16x8*)&lA[p][lofs] = ap;
    *(u16x8*)&lB[p][lofs] = bv;
    if (k0 + 32 < K) {   // prefetch next K-tile; lands under current MFMA
      a4[0] = *(const f32x4*)(Ag + k0 + 32);
      a4[1] = *(const f32x4*)(Ag + k0 + 36);
      bv    = *(const u16x8*)(Bg + k0 + 32);
    }
    __syncthreads();  // buf[p] complete (other buf untouched -> 1 barrier ok)

    bf16x8 af[2], bb[2];
#pragma unroll
    for (int i = 0; i < 2; ++i) {
      const int row = wm + i * 16 + fr;
      af[i] = *(const bf16x8*)&lA[p][row * 32 + (fq ^ (row & 3)) * 8];
    }
#pragma unroll
    for (int j = 0; j < 2; ++j) {
      const int row = wn + j * 16 + fr;
      bb[j] = *(const bf16x8*)&lB[p][row * 32 + (fq ^ (row & 3)) * 8];
    }
#pragma unroll
    for (int i = 0; i < 2; ++i)
#pragma unroll
      for (int j = 0; j < 2; ++j)
        acc[i][j] = __builtin_amdgcn_mfma_f32_16x16x32_bf16(af[i], bb[j], acc[i][j], 0, 0, 0);
  }

#pragma unroll
  for (int i = 0; i < 2; ++i) {
    const int ob = m0 + wm + i * 16 + fq * 4;   // o base, multiple of 4
    const f32x4 s4 = *(const f32x4*)&scale[ob];
    const f32x4 b4 = *(const f32x4*)&bias[ob];
#pragma unroll
    for (int j = 0; j < 2; ++j) {
      const int P = n0 + wn + j * 16 + fr;
      if (MODE == 0) {
        unsigned short* Cout = (unsigned short*)CoutV;
        u16x4 pk;
#pragma unroll
        for (int rr = 0; rr < 4; ++rr) {
          float v = acc[i][j][rr] * s4[rr] + b4[rr];
          if (do_relu) v = fmaxf(v, 0.0f);
          pk[rr] = f2bf(v);
        }
        *(u16x4*)&Cout[(size_t)P * 256 + ob] = pk;
      } else {
        float* Cout = (float*)CoutV;
        const size_t base = (size_t)(P >> 10) * 1048576 + (size_t)(P & 1023);
#pragma unroll
        for (int rr = 0; rr < 4; ++rr) {
          const size_t addr = base + (size_t)(ob + rr) * 1024;
          float v = acc[i][j][rr] * s4[rr] + b4[rr] + resid[addr];
          Cout[addr] = fmaxf(v, 0.0f);
        }
      }
    }
  }
}

// ---------------------------------------------------------------------------
// Local 3x3 attention. Thread = (pixel slot s=tid>>5, head g=tid&31).
// S_t = q.k_nb + q.ph(i) + q.pw(j)  (k_nb = 0 when OOB; pos term always added).
// softmax over 9 taps; out = sum_t attn_t * v_nb (v_nb = 0 OOB); relu(bn(out)).
__global__ __launch_bounds__(256, 4) void k_attn(
    const unsigned short* __restrict__ Q, const unsigned short* __restrict__ Kb,
    const unsigned short* __restrict__ Vb, unsigned short* __restrict__ O,
    const float* __restrict__ pos_h, const float* __restrict__ pos_w,
    const float* __restrict__ bs, const float* __restrict__ bb) {
  __shared__ float ph_l[3][256];
  __shared__ float pw_l[3][256];
  {
    const int c = threadIdx.x;
#pragma unroll
    for (int i = 0; i < 3; ++i) {
      ph_l[i][c] = pos_h[c * 3 + i];
      pw_l[i][c] = pos_w[c * 3 + i];
    }
  }
  __syncthreads();
  const int tid = threadIdx.x;
  const int g = tid & 31, s = tid >> 5;
  const int P = blockIdx.x * 8 + s;
  const int b = P >> 10, pix = P & 1023;
  const int hh = pix >> 5, ww = pix & 31;
  const int c0 = g * 8;

  float qf[8];
  {
    u16x8 qv = *(const u16x8*)&Q[(size_t)P * 256 + c0];
#pragma unroll
    for (int d = 0; d < 8; ++d) qf[d] = bf2f(qv[d]);
  }
  float Ai[3], Bj[3];
#pragma unroll
  for (int i = 0; i < 3; ++i) {
    float a = 0.f, w = 0.f;
#pragma unroll
    for (int d = 0; d < 8; ++d) {
      a += qf[d] * ph_l[i][c0 + d];
      w += qf[d] * pw_l[i][c0 + d];
    }
    Ai[i] = a; Bj[i] = w;
  }

  float S[9];
  int nPs[9];
#pragma unroll
  for (int t = 0; t < 9; ++t) {
    const int di = t / 3, dj = t % 3;
    const int nh = hh + di - 1, nw = ww + dj - 1;
    float sum = Ai[di] + Bj[dj];
    int nP = -1;
    if ((unsigned)nh < 32u && (unsigned)nw < 32u) {
      nP = (b << 10) + (nh << 5) + nw;
      u16x8 kv = *(const u16x8*)&Kb[(size_t)nP * 256 + c0];
#pragma unroll
      for (int d = 0; d < 8; ++d) sum += qf[d] * bf2f(kv[d]);
    }
    nPs[t] = nP;
    S[t] = sum;
  }

  float mx = S[0];
#pragma unroll
  for (int t = 1; t < 9; ++t) mx = fmaxf(mx, S[t]);
  float e[9], tot = 0.f;
#pragma unroll
  for (int t = 0; t < 9; ++t) { e[t] = __expf(S[t] - mx); tot += e[t]; }
  const float inv = 1.0f / tot;

  float of[8] = {0.f, 0.f, 0.f, 0.f, 0.f, 0.f, 0.f, 0.f};
#pragma unroll
  for (int t = 0; t < 9; ++t) {
    if (nPs[t] >= 0) {
      u16x8 vv = *(const u16x8*)&Vb[(size_t)nPs[t] * 256 + c0];
      const float w = e[t] * inv;
#pragma unroll
      for (int d = 0; d < 8; ++d) of[d] += w * bf2f(vv[d]);
    }
  }

  u16x8 res;
#pragma unroll
  for (int d = 0; d < 8; ++d) {
    float v = of[d] * bs[c0 + d] + bb[c0 + d];
    v = fmaxf(v, 0.0f);
    res[d] = f2bf(v);
  }
  *(u16x8*)&O[(size_t)P * 256 + c0] = res;
}

// ---------------------------------------------------------------------------
extern "C" void kernel_launch(void* const* d_in, const int* in_sizes, int n_in,
                              void* d_out, int out_size, void* d_ws, size_t ws_size,
                              hipStream_t stream) {
  (void)in_sizes; (void)n_in; (void)out_size; (void)ws_size;
  const float* x       = (const float*)d_in[0];
  const float* w1      = (const float*)d_in[1];
  const float* bn1_s   = (const float*)d_in[2];
  const float* bn1_b   = (const float*)d_in[3];
  const float* wq      = (const float*)d_in[4];
  const float* bnq_s   = (const float*)d_in[5];
  const float* bnq_b   = (const float*)d_in[6];
  const float* wk      = (const float*)d_in[7];
  const float* bnk_s   = (const float*)d_in[8];
  const float* bnk_b   = (const float*)d_in[9];
  const float* wv      = (const float*)d_in[10];
  const float* bnv_s   = (const float*)d_in[11];
  const float* bnv_b   = (const float*)d_in[12];
  const float* pos_h   = (const float*)d_in[13];
  const float* pos_w   = (const float*)d_in[14];
  const float* bnatt_s = (const float*)d_in[15];
  const float* bnatt_b = (const float*)d_in[16];
  const float* w3      = (const float*)d_in[17];
  const float* bn3_s   = (const float*)d_in[18];
  const float* bn3_b   = (const float*)d_in[19];

  char* ws = (char*)d_ws;
  unsigned short* h1t = (unsigned short*)(ws);
  unsigned short* qt  = (unsigned short*)(ws + 8388608);
  unsigned short* ktt = (unsigned short*)(ws + 16777216);
  unsigned short* vtt = (unsigned short*)(ws + 25165824);
  unsigned short* att = h1t;
  unsigned short* xt  = (unsigned short*)d_out;

  k_transpose_x<<<dim3(32, 32, 16), dim3(256), 0, stream>>>(x, xt);

  // conv1: M=256, N=16384, K=1024 -> grid (N/64, M/64) = (256,4) = 1024 blocks
  k_gemm<0><<<dim3(256, 4), dim3(256), 0, stream>>>(w1, xt, h1t, bn1_s, bn1_b,
                                                    nullptr, 1024, 1);
  // q, k, v: M=256, N=16384, K=256
  k_gemm<0><<<dim3(256, 4), dim3(256), 0, stream>>>(wq, h1t, qt, bnq_s, bnq_b,
                                                    nullptr, 256, 1);
  k_gemm<0><<<dim3(256, 4), dim3(256), 0, stream>>>(wk, h1t, ktt, bnk_s, bnk_b,
                                                    nullptr, 256, 1);
  k_gemm<0><<<dim3(256, 4), dim3(256), 0, stream>>>(wv, h1t, vtt, bnv_s, bnv_b,
                                                    nullptr, 256, 0);

  k_attn<<<dim3(2048), dim3(256), 0, stream>>>(qt, ktt, vtt, att, pos_h, pos_w,
                                               bnatt_s, bnatt_b);

  // conv3 + residual + relu -> d_out (f32), M=1024, N=16384, K=256
  k_gemm<1><<<dim3(256, 16), dim3(256), 0, stream>>>(w3, att, d_out,
                                                     bn3_s, bn3_b, x, 256, 1);
}

// Round 5
// 113.266 us; speedup vs baseline: 1.2296x; 1.0424x over previous
//
#include <hip/hip_runtime.h>
#include <stdint.h>

// ---------------------------------------------------------------------------
// Bottleneck with 3x3 local self-attention, MI355X (gfx950).
// R5: conv3 was 40us latency-bound (8 K-steps/block, cold-start dominated).
//  - New k_gemm_k256: A-tile (64x256) staged in LDS ONCE per block,
//    persistent over NT=4 n-tiles, B double-buffered w/ cross-tile register
//    prefetch, 1 barrier/K-step. LDS 40KB -> 4 blocks/CU.
//  - q,k,v fused into ONE dispatch (segment-indexed weights/outputs).
// Layout: activations (pix, C) bf16; 1x1 conv = gemm_bt:
//   D[o][P] = sum_k W[o][k] * Act[P][k], MFMA 16x16x32 bf16.
// ws (32 MiB): h1t@0 (att aliases after qkv), q@8MiB, k@16MiB, v@24MiB.
// xt (32MiB bf16) staged in d_out's first half (f32 64MiB), dead before conv3.
// ---------------------------------------------------------------------------

typedef __attribute__((ext_vector_type(4))) float f32x4;
typedef __attribute__((ext_vector_type(8))) __bf16 bf16x8;
typedef __attribute__((ext_vector_type(4))) unsigned short u16x4;
typedef __attribute__((ext_vector_type(8))) unsigned short u16x8;

__device__ __forceinline__ float bf2f(unsigned short u) {
  union { unsigned int i; float f; } c; c.i = ((unsigned int)u) << 16; return c.f;
}
__device__ __forceinline__ unsigned short f2bf(float f) {
  union { float f; unsigned int i; } c; c.f = f;
  unsigned int x = c.i;
  return (unsigned short)((x + 0x7FFFu + ((x >> 16) & 1u)) >> 16);
}

// ---------------------------------------------------------------------------
// x (16,1024ch,1024pix) f32 -> xt (16,1024pix,1024ch) bf16, LDS tile transpose.
__global__ __launch_bounds__(256) void k_transpose_x(const float* __restrict__ x,
                                                     unsigned short* __restrict__ xt) {
  __shared__ float tile[32][33];
  const int b  = blockIdx.z;
  const int c0 = blockIdx.y * 32;
  const int p0 = blockIdx.x * 32;
  const int tx = threadIdx.x & 31;
  const int ty = threadIdx.x >> 5;  // 0..7
  const float* xb = x + (size_t)b * 1048576;
  unsigned short* xtb = xt + (size_t)b * 1048576;
#pragma unroll
  for (int i = 0; i < 4; ++i)
    tile[ty + i * 8][tx] = xb[(size_t)(c0 + ty + i * 8) * 1024 + p0 + tx];
  __syncthreads();
#pragma unroll
  for (int i = 0; i < 4; ++i)
    xtb[(size_t)(p0 + ty + i * 8) * 1024 + c0 + tx] = f2bf(tile[tx][ty + i * 8]);
}

// ---------------------------------------------------------------------------
// Streaming gemm_bt for conv1 (K=1024). 64x64 tile, BK=32, dbuf, reg-prefetch.
__global__ __launch_bounds__(256, 4) void k_gemm_stream(
    const float* __restrict__ A, const unsigned short* __restrict__ B,
    unsigned short* __restrict__ Cout, const float* __restrict__ scale,
    const float* __restrict__ bias, int K) {
  __shared__ unsigned short lA[2][64 * 32];
  __shared__ unsigned short lB[2][64 * 32];
  const int m0  = blockIdx.y * 64;
  const int n0  = blockIdx.x * 64;
  const int tid = threadIdx.x;
  const int lane = tid & 63;
  const int wid  = tid >> 6;
  const int wm = (wid >> 1) * 32, wn = (wid & 1) * 32;
  const int fr = lane & 15, fq = lane >> 4;

  f32x4 acc[2][2] = {};

  const int r = tid >> 2;
  const int g = tid & 3;
  const float*          Ag = A + (size_t)(m0 + r) * K + g * 8;
  const unsigned short* Bg = B + (size_t)(n0 + r) * K + g * 8;
  const int lofs = r * 32 + (g ^ (r & 3)) * 8;

  f32x4 a4[2];
  u16x8 bv;
  a4[0] = *(const f32x4*)(Ag);
  a4[1] = *(const f32x4*)(Ag + 4);
  bv    = *(const u16x8*)(Bg);

  int p = 0;
  for (int k0 = 0; k0 < K; k0 += 32, p ^= 1) {
    u16x8 ap;
#pragma unroll
    for (int i = 0; i < 8; ++i) ap[i] = f2bf(a4[i >> 2][i & 3]);
    *(u16x8*)&lA[p][lofs] = ap;
    *(u16x8*)&lB[p][lofs] = bv;
    if (k0 + 32 < K) {
      a4[0] = *(const f32x4*)(Ag + k0 + 32);
      a4[1] = *(const f32x4*)(Ag + k0 + 36);
      bv    = *(const u16x8*)(Bg + k0 + 32);
    }
    __syncthreads();

    bf16x8 af[2], bb[2];
#pragma unroll
    for (int i = 0; i < 2; ++i) {
      const int row = wm + i * 16 + fr;
      af[i] = *(const bf16x8*)&lA[p][row * 32 + (fq ^ (row & 3)) * 8];
    }
#pragma unroll
    for (int j = 0; j < 2; ++j) {
      const int row = wn + j * 16 + fr;
      bb[j] = *(const bf16x8*)&lB[p][row * 32 + (fq ^ (row & 3)) * 8];
    }
#pragma unroll
    for (int i = 0; i < 2; ++i)
#pragma unroll
      for (int j = 0; j < 2; ++j)
        acc[i][j] = __builtin_amdgcn_mfma_f32_16x16x32_bf16(af[i], bb[j], acc[i][j], 0, 0, 0);
  }

#pragma unroll
  for (int i = 0; i < 2; ++i) {
    const int ob = m0 + wm + i * 16 + fq * 4;
    const f32x4 s4 = *(const f32x4*)&scale[ob];
    const f32x4 b4 = *(const f32x4*)&bias[ob];
#pragma unroll
    for (int j = 0; j < 2; ++j) {
      const int P = n0 + wn + j * 16 + fr;
      u16x4 pk;
#pragma unroll
      for (int rr = 0; rr < 4; ++rr) {
        float v = fmaxf(acc[i][j][rr] * s4[rr] + b4[rr], 0.0f);
        pk[rr] = f2bf(v);
      }
      *(u16x4*)&Cout[(size_t)P * 256 + ob] = pk;
    }
  }
}

// ---------------------------------------------------------------------------
// K=256 persistent gemm_bt. A-tile (64x256 bf16, 32KB) staged ONCE with
// swizzle cg^=(row&7)<<2 (8 lanes/bank-quad = optimal for ds_read_b128).
// Block iterates NT n-tiles; B (64x32) double-buffered, reg prefetch crosses
// tile boundaries; one barrier per K-step. LDS 40KB -> 4 blocks/CU.
// MODE 0 (fused qkv): seg = mt>>2 picks A0..2/s/b; out = Cout + seg*4MiB elems;
//                     relu for seg<2 (q,k), none for v.
// MODE 1 (conv3): f32 out with residual + relu, d_out[b][o][pix] layout.
template <int MODE, int NT>
__global__ __launch_bounds__(256, 4) void k_gemm_k256(
    const float* __restrict__ A0, const float* __restrict__ A1,
    const float* __restrict__ A2, const unsigned short* __restrict__ B,
    void* __restrict__ CoutV,
    const float* __restrict__ s0, const float* __restrict__ s1,
    const float* __restrict__ s2, const float* __restrict__ b0,
    const float* __restrict__ b1, const float* __restrict__ b2,
    const float* __restrict__ resid) {
  __shared__ unsigned short lA[64 * 256];
  __shared__ unsigned short lB[2][64 * 32];
  const int mt = blockIdx.y;
  int seg, m_loc, do_relu;
  const float *A, *sc, *bi;
  if (MODE == 0) {
    seg = mt >> 2; m_loc = (mt & 3) * 64;
    A  = seg == 0 ? A0 : (seg == 1 ? A1 : A2);
    sc = seg == 0 ? s0 : (seg == 1 ? s1 : s2);
    bi = seg == 0 ? b0 : (seg == 1 ? b1 : b2);
    do_relu = (seg < 2);
  } else {
    seg = 0; m_loc = mt * 64; A = A0; sc = s0; bi = b0; do_relu = 1;
  }
  const int tid = threadIdx.x;
  const int lane = tid & 63, wid = tid >> 6;
  const int wm = (wid >> 1) * 32, wn = (wid & 1) * 32;
  const int fr = lane & 15, fq = lane >> 4;

  // ---- stage A once: thread -> row rA=t>>2, quarter qd=t&3 (64 cols) ----
  {
    const int rA = tid >> 2, qd = tid & 3;
    const float* Ag = A + (size_t)(m_loc + rA) * 256 + qd * 64;
#pragma unroll
    for (int m = 0; m < 8; ++m) {
      f32x4 lo = *(const f32x4*)(Ag + m * 8);
      f32x4 hi = *(const f32x4*)(Ag + m * 8 + 4);
      u16x8 pk;
#pragma unroll
      for (int e = 0; e < 4; ++e) pk[e] = f2bf(lo[e]);
#pragma unroll
      for (int e = 0; e < 4; ++e) pk[4 + e] = f2bf(hi[e]);
      const int cg = qd * 8 + m;  // 0..31
      *(u16x8*)&lA[rA * 256 + (cg ^ ((rA & 7) << 2)) * 8] = pk;
    }
  }

  // ---- B staging setup ----
  const int rB = tid >> 2, gB = tid & 3;
  const int lofsB = rB * 32 + (gB ^ (rB & 3)) * 8;
  const int n0_blk = blockIdx.x * NT * 64;
  const unsigned short* Bg = B + (size_t)(n0_blk + rB) * 256 + gB * 8;

  u16x8 bv = *(const u16x8*)(Bg);  // tile 0, k0 = 0
  f32x4 acc[2][2] = {};
  int p = 0;
  const int TOT = NT * 8;

  for (int s = 0; s < TOT; ++s) {
    const int k0 = (s & 7) * 32;
    *(u16x8*)&lB[p][lofsB] = bv;
    if (s + 1 < TOT) {
      const int s1i = s + 1;
      bv = *(const u16x8*)(Bg + (size_t)(s1i >> 3) * 16384 + (s1i & 7) * 32);
    }
    __syncthreads();  // covers A-stage (s=0) and lB[p]; dbuf makes 1 barrier safe

    bf16x8 af[2], bb[2];
#pragma unroll
    for (int i = 0; i < 2; ++i) {
      const int row = wm + i * 16 + fr;
      const int cg = (k0 >> 3) + fq;
      af[i] = *(const bf16x8*)&lA[row * 256 + (cg ^ ((row & 7) << 2)) * 8];
    }
#pragma unroll
    for (int j = 0; j < 2; ++j) {
      const int row = wn + j * 16 + fr;
      bb[j] = *(const bf16x8*)&lB[p][row * 32 + (fq ^ (row & 3)) * 8];
    }
#pragma unroll
    for (int i = 0; i < 2; ++i)
#pragma unroll
      for (int j = 0; j < 2; ++j)
        acc[i][j] = __builtin_amdgcn_mfma_f32_16x16x32_bf16(af[i], bb[j], acc[i][j], 0, 0, 0);
    p ^= 1;

    if ((s & 7) == 7) {  // epilogue for tile it (global IO only, no LDS)
      const int n0 = n0_blk + (s >> 3) * 64;
#pragma unroll
      for (int i = 0; i < 2; ++i) {
        const int ol = m_loc + wm + i * 16 + fq * 4;  // local o in segment
        const f32x4 s4 = *(const f32x4*)&sc[ol];
        const f32x4 b4 = *(const f32x4*)&bi[ol];
#pragma unroll
        for (int j = 0; j < 2; ++j) {
          const int P = n0 + wn + j * 16 + fr;
          if (MODE == 0) {
            unsigned short* Cout = (unsigned short*)CoutV + (size_t)seg * 4194304;
            u16x4 pk;
#pragma unroll
            for (int rr = 0; rr < 4; ++rr) {
              float v = acc[i][j][rr] * s4[rr] + b4[rr];
              if (do_relu) v = fmaxf(v, 0.0f);
              pk[rr] = f2bf(v);
            }
            *(u16x4*)&Cout[(size_t)P * 256 + ol] = pk;
          } else {
            float* Cout = (float*)CoutV;
            const size_t base = (size_t)(P >> 10) * 1048576 + (size_t)(P & 1023);
#pragma unroll
            for (int rr = 0; rr < 4; ++rr) {
              const size_t addr = base + (size_t)(ol + rr) * 1024;
              float v = acc[i][j][rr] * s4[rr] + b4[rr] + resid[addr];
              Cout[addr] = fmaxf(v, 0.0f);
            }
          }
          acc[i][j] = (f32x4){0.f, 0.f, 0.f, 0.f};
        }
      }
    }
  }
}

// ---------------------------------------------------------------------------
// Local 3x3 attention. Thread = (pixel slot s=tid>>5, head g=tid&31).
__global__ __launch_bounds__(256, 4) void k_attn(
    const unsigned short* __restrict__ Q, const unsigned short* __restrict__ Kb,
    const unsigned short* __restrict__ Vb, unsigned short* __restrict__ O,
    const float* __restrict__ pos_h, const float* __restrict__ pos_w,
    const float* __restrict__ bs, const float* __restrict__ bb) {
  __shared__ float ph_l[3][256];
  __shared__ float pw_l[3][256];
  {
    const int c = threadIdx.x;
#pragma unroll
    for (int i = 0; i < 3; ++i) {
      ph_l[i][c] = pos_h[c * 3 + i];
      pw_l[i][c] = pos_w[c * 3 + i];
    }
  }
  __syncthreads();
  const int tid = threadIdx.x;
  const int g = tid & 31, s = tid >> 5;
  const int P = blockIdx.x * 8 + s;
  const int b = P >> 10, pix = P & 1023;
  const int hh = pix >> 5, ww = pix & 31;
  const int c0 = g * 8;

  float qf[8];
  {
    u16x8 qv = *(const u16x8*)&Q[(size_t)P * 256 + c0];
#pragma unroll
    for (int d = 0; d < 8; ++d) qf[d] = bf2f(qv[d]);
  }
  float Ai[3], Bj[3];
#pragma unroll
  for (int i = 0; i < 3; ++i) {
    float a = 0.f, w = 0.f;
#pragma unroll
    for (int d = 0; d < 8; ++d) {
      a += qf[d] * ph_l[i][c0 + d];
      w += qf[d] * pw_l[i][c0 + d];
    }
    Ai[i] = a; Bj[i] = w;
  }

  float S[9];
  int nPs[9];
#pragma unroll
  for (int t = 0; t < 9; ++t) {
    const int di = t / 3, dj = t % 3;
    const int nh = hh + di - 1, nw = ww + dj - 1;
    float sum = Ai[di] + Bj[dj];
    int nP = -1;
    if ((unsigned)nh < 32u && (unsigned)nw < 32u) {
      nP = (b << 10) + (nh << 5) + nw;
      u16x8 kv = *(const u16x8*)&Kb[(size_t)nP * 256 + c0];
#pragma unroll
      for (int d = 0; d < 8; ++d) sum += qf[d] * bf2f(kv[d]);
    }
    nPs[t] = nP;
    S[t] = sum;
  }

  float mx = S[0];
#pragma unroll
  for (int t = 1; t < 9; ++t) mx = fmaxf(mx, S[t]);
  float e[9], tot = 0.f;
#pragma unroll
  for (int t = 0; t < 9; ++t) { e[t] = __expf(S[t] - mx); tot += e[t]; }
  const float inv = 1.0f / tot;

  float of[8] = {0.f, 0.f, 0.f, 0.f, 0.f, 0.f, 0.f, 0.f};
#pragma unroll
  for (int t = 0; t < 9; ++t) {
    if (nPs[t] >= 0) {
      u16x8 vv = *(const u16x8*)&Vb[(size_t)nPs[t] * 256 + c0];
      const float w = e[t] * inv;
#pragma unroll
      for (int d = 0; d < 8; ++d) of[d] += w * bf2f(vv[d]);
    }
  }

  u16x8 res;
#pragma unroll
  for (int d = 0; d < 8; ++d) {
    float v = of[d] * bs[c0 + d] + bb[c0 + d];
    v = fmaxf(v, 0.0f);
    res[d] = f2bf(v);
  }
  *(u16x8*)&O[(size_t)P * 256 + c0] = res;
}

// ---------------------------------------------------------------------------
extern "C" void kernel_launch(void* const* d_in, const int* in_sizes, int n_in,
                              void* d_out, int out_size, void* d_ws, size_t ws_size,
                              hipStream_t stream) {
  (void)in_sizes; (void)n_in; (void)out_size; (void)ws_size;
  const float* x       = (const float*)d_in[0];
  const float* w1      = (const float*)d_in[1];
  const float* bn1_s   = (const float*)d_in[2];
  const float* bn1_b   = (const float*)d_in[3];
  const float* wq      = (const float*)d_in[4];
  const float* bnq_s   = (const float*)d_in[5];
  const float* bnq_b   = (const float*)d_in[6];
  const float* wk      = (const float*)d_in[7];
  const float* bnk_s   = (const float*)d_in[8];
  const float* bnk_b   = (const float*)d_in[9];
  const float* wv      = (const float*)d_in[10];
  const float* bnv_s   = (const float*)d_in[11];
  const float* bnv_b   = (const float*)d_in[12];
  const float* pos_h   = (const float*)d_in[13];
  const float* pos_w   = (const float*)d_in[14];
  const float* bnatt_s = (const float*)d_in[15];
  const float* bnatt_b = (const float*)d_in[16];
  const float* w3      = (const float*)d_in[17];
  const float* bn3_s   = (const float*)d_in[18];
  const float* bn3_b   = (const float*)d_in[19];

  char* ws = (char*)d_ws;
  unsigned short* h1t = (unsigned short*)(ws);
  unsigned short* qt  = (unsigned short*)(ws + 8388608);  // k @ +8MiB, v @ +16MiB
  unsigned short* att = h1t;
  unsigned short* xt  = (unsigned short*)d_out;

  k_transpose_x<<<dim3(32, 32, 16), dim3(256), 0, stream>>>(x, xt);

  // conv1: M=256, N=16384, K=1024
  k_gemm_stream<<<dim3(256, 4), dim3(256), 0, stream>>>(w1, xt, h1t, bn1_s, bn1_b, 1024);

  // fused q,k,v: 12 m-tiles (4 per segment), 64 n-blocks x NT=4
  k_gemm_k256<0, 4><<<dim3(64, 12), dim3(256), 0, stream>>>(
      wq, wk, wv, h1t, qt, bnq_s, bnk_s, bnv_s, bnq_b, bnk_b, bnv_b, nullptr);

  k_attn<<<dim3(2048), dim3(256), 0, stream>>>(qt, qt + 4194304, qt + 8388608, att,
                                               pos_h, pos_w, bnatt_s, bnatt_b);

  // conv3 + residual + relu -> d_out (f32), M=1024, N=16384, K=256
  k_gemm_k256<1, 4><<<dim3(64, 16), dim3(256), 0, stream>>>(
      w3, nullptr, nullptr, att, d_out, bn3_s, nullptr, nullptr, bn3_b, nullptr,
      nullptr, x);
}